// Round 1
// baseline (1099.163 us; speedup 1.0000x reference)
//
#include <hip/hip_runtime.h>

#define NB 2048      // batch
#define FEAT 2048
#define NBINS 9
#define NATTR 12
#define NPT 20
#define DD 64
#define HH 256

// ---------------------------------------------------------------- K0: weight prep
// WT[c][k], c in [0,21): c<9 -> nima_Wl col c, else nima_Wa col c-9
__global__ void k_prep_wt(const float* __restrict__ Wl, const float* __restrict__ Wa,
                          float* __restrict__ WT) {
  int idx = blockIdx.x * 256 + threadIdx.x;
  if (idx >= 21 * FEAT) return;
  int c = idx / FEAT, k = idx - c * FEAT;
  WT[idx] = (c < NBINS) ? Wl[k * NBINS + c] : Wa[k * NATTR + (c - NBINS)];
}

// ---------------------------------------------------------------- K1: NIMA heads
// one wave per row; float4 loads; butterfly reduce 21 accumulators
__global__ __launch_bounds__(256) void k_nima(
    const float* __restrict__ A, const float* __restrict__ WT,
    const float* __restrict__ bl, const float* __restrict__ ba,
    float* __restrict__ logit, float* __restrict__ attr_raw) {
  int wave = threadIdx.x >> 6, lane = threadIdx.x & 63;
  int row = blockIdx.x * 4 + wave;
  const float4* A4 = (const float4*)(A + (size_t)row * FEAT);
  float acc[21];
#pragma unroll
  for (int c = 0; c < 21; ++c) acc[c] = 0.f;
#pragma unroll
  for (int it = 0; it < 8; ++it) {
    int kk = it * 64 + lane;          // float4 index, 0..511
    float4 a = A4[kk];
#pragma unroll
    for (int c = 0; c < 21; ++c) {
      float4 w = ((const float4*)(WT + c * FEAT))[kk];
      acc[c] += a.x * w.x + a.y * w.y + a.z * w.z + a.w * w.w;
    }
  }
#pragma unroll
  for (int c = 0; c < 21; ++c) {
#pragma unroll
    for (int m = 1; m < 64; m <<= 1) acc[c] += __shfl_xor(acc[c], m);
  }
  if (lane == 0) {
#pragma unroll
    for (int c = 0; c < NBINS; ++c) logit[row * NBINS + c] = acc[c] + bl[c];
#pragma unroll
    for (int c = 0; c < NATTR; ++c) attr_raw[row * NATTR + c] = acc[NBINS + c] + ba[c];
  }
}

// ---------------------------------------------------------------- K2: direct path
// softmax(logit)*scale -> MLP(9->256->1); one wave per batch row
__global__ __launch_bounds__(256) void k_direct(
    const float* __restrict__ logit, const float* __restrict__ W1,
    const float* __restrict__ b1, const float* __restrict__ W2,
    const float* __restrict__ b2, float* __restrict__ direct) {
  int wave = threadIdx.x >> 6, lane = threadIdx.x & 63;
  int b = blockIdx.x * 4 + wave;
  const float* lg = logit + b * NBINS;
  float l[NBINS];
  float m = -1e30f;
#pragma unroll
  for (int i = 0; i < NBINS; ++i) { l[i] = lg[i]; m = fmaxf(m, l[i]); }
  float s = 0.f;
#pragma unroll
  for (int i = 0; i < NBINS; ++i) { l[i] = expf(l[i] - m); s += l[i]; }
  float inv = 1.f / s;
#pragma unroll
  for (int i = 0; i < NBINS; ++i) l[i] *= inv * (1.f + 0.5f * (float)i);
  float partial = 0.f;
#pragma unroll
  for (int hh = 0; hh < 4; ++hh) {
    int h = lane + hh * 64;
    float v = b1[h];
#pragma unroll
    for (int i = 0; i < NBINS; ++i) v += l[i] * W1[i * HH + h];
    v = fmaxf(v, 0.f);
    partial += v * W2[h];
  }
#pragma unroll
  for (int m2 = 1; m2 < 64; m2 <<= 1) partial += __shfl_xor(partial, m2);
  if (lane == 0) direct[b] = partial + b2[0];
}

// ---------------------------------------------------------------- K3: node MLPs
// X[B,DIN] -> relu(X@W1+b1) -> @W2[256,768]+b2 -> out[B,768]; 8 rows per block
template <int DIN>
__global__ __launch_bounds__(256) void k_node_mlp(
    const float* __restrict__ X, const float* __restrict__ W1,
    const float* __restrict__ b1, const float* __restrict__ W2,
    const float* __restrict__ b2, float* __restrict__ out) {
  __shared__ __align__(16) float hlds[HH * 8];
  int h = threadIdx.x;
  int r0 = blockIdx.x * 8;
  float w1r[DIN];
#pragma unroll
  for (int d = 0; d < DIN; ++d) w1r[d] = W1[d * HH + h];
  float b1h = b1[h];
#pragma unroll
  for (int r = 0; r < 8; ++r) {
    const float* x = X + (size_t)(r0 + r) * DIN;
    float s = b1h;
#pragma unroll
    for (int d = 0; d < DIN; ++d) s += x[d] * w1r[d];
    hlds[h * 8 + r] = fmaxf(s, 0.f);
  }
  __syncthreads();
  float acc[3][8];
#pragma unroll
  for (int oi = 0; oi < 3; ++oi)
#pragma unroll
    for (int r = 0; r < 8; ++r) acc[oi][r] = 0.f;
  for (int hh = 0; hh < HH; ++hh) {
    float4 a = ((const float4*)(hlds + hh * 8))[0];
    float4 bv = ((const float4*)(hlds + hh * 8))[1];
    float hv[8] = {a.x, a.y, a.z, a.w, bv.x, bv.y, bv.z, bv.w};
#pragma unroll
    for (int oi = 0; oi < 3; ++oi) {
      float w = W2[hh * 768 + threadIdx.x + oi * 256];
#pragma unroll
      for (int r = 0; r < 8; ++r) acc[oi][r] += hv[r] * w;
    }
  }
#pragma unroll
  for (int oi = 0; oi < 3; ++oi) {
    int o = threadIdx.x + oi * 256;
    float bb = b2[o];
#pragma unroll
    for (int r = 0; r < 8; ++r) out[(size_t)(r0 + r) * 768 + o] = acc[oi][r] + bb;
  }
}

// ---------------------------------------------------------------- K4: internal interaction
// block = (b, img/user); thread h holds W1[:,h] in regs; symmetric pairs;
// q columns private per thread in LDS; then W2 phase.
__global__ __launch_bounds__(256) void k_internal(
    const float* __restrict__ attr_img, const float* __restrict__ attr_user,
    const float* __restrict__ W1i, const float* __restrict__ b1i,
    const float* __restrict__ W2i, const float* __restrict__ b2i,
    const float* __restrict__ W1u, const float* __restrict__ b1u,
    const float* __restrict__ W2u, const float* __restrict__ b2u,
    float* __restrict__ out_img, float* __restrict__ out_user) {
  int b = blockIdx.x, dt = blockIdx.y;
  const float* e = (dt == 0 ? attr_img : attr_user) + (size_t)b * (NATTR * DD);
  const float* W1 = dt == 0 ? W1i : W1u;
  const float* b1 = dt == 0 ? b1i : b1u;
  const float* W2 = dt == 0 ? W2i : W2u;
  const float* b2 = dt == 0 ? b2i : b2u;
  float* outp = (dt == 0 ? out_img : out_user) + (size_t)b * (NATTR * DD);

  __shared__ __align__(16) float qlds[NATTR * HH];
  int h = threadIdx.x;
  float w1c[DD];
#pragma unroll
  for (int d = 0; d < DD; ++d) w1c[d] = W1[d * HH + h];
  float b1h = b1[h];
#pragma unroll
  for (int jj = 0; jj < NATTR; ++jj) qlds[jj * HH + h] = 0.f;

  for (int j = 0; j < NATTR; ++j) {
    float u[DD];
    const float4* ej4 = (const float4*)(e + j * DD);
#pragma unroll
    for (int dc = 0; dc < 16; ++dc) {
      float4 v = ej4[dc];
      u[4 * dc + 0] = v.x * w1c[4 * dc + 0];
      u[4 * dc + 1] = v.y * w1c[4 * dc + 1];
      u[4 * dc + 2] = v.z * w1c[4 * dc + 2];
      u[4 * dc + 3] = v.w * w1c[4 * dc + 3];
    }
    float qj = 0.f;
    for (int i = 0; i <= j; ++i) {
      const float4* ei4 = (const float4*)(e + i * DD);
      float s = b1h;
#pragma unroll
      for (int dc = 0; dc < 16; ++dc) {
        float4 v = ei4[dc];
        s += v.x * u[4 * dc + 0] + v.y * u[4 * dc + 1] +
             v.z * u[4 * dc + 2] + v.w * u[4 * dc + 3];
      }
      float r = fmaxf(s, 0.f);
      qj += r;
      if (i < j) qlds[i * HH + h] += r;  // symmetric partner; thread-private column
    }
    qlds[j * HH + h] += qj;
  }
  __syncthreads();

  // W2 phase: out[j][d'] = sum_h q[j][h] * W2[h][d'] + 12*b2[d']
#pragma unroll
  for (int oi = 0; oi < 3; ++oi) {
    int o = threadIdx.x + oi * 256;
    int jr = o >> 6, dp = o & 63;
    float acc = 0.f;
    const float4* q4 = (const float4*)(qlds + jr * HH);
    for (int hc = 0; hc < 64; ++hc) {
      float4 qv = q4[hc];
      acc += qv.x * W2[(hc * 4 + 0) * DD + dp];
      acc += qv.y * W2[(hc * 4 + 1) * DD + dp];
      acc += qv.z * W2[(hc * 4 + 2) * DD + dp];
      acc += qv.w * W2[(hc * 4 + 3) * DD + dp];
    }
    outp[o] = acc + 12.f * b2[dp];
  }
}

// ---------------------------------------------------------------- Kext: attr column sums
__global__ __launch_bounds__(64) void k_colsum(
    const float* __restrict__ attr_img, const float* __restrict__ attr_user,
    float* __restrict__ cs_img, float* __restrict__ cs_user) {
  int b = blockIdx.x, d = threadIdx.x;
  const float* ei = attr_img + (size_t)b * (NATTR * DD);
  const float* eu = attr_user + (size_t)b * (NATTR * DD);
  float si = 0.f, su = 0.f;
#pragma unroll
  for (int a = 0; a < NATTR; ++a) { si += ei[a * DD + d]; su += eu[a * DD + d]; }
  cs_img[b * DD + d] = si;
  cs_user[b * DD + d] = su;
}

// ---------------------------------------------------------------- K5: GRU fuse + head
// block per b, 192 threads (thread = gate column g); both img & user; epilogue writes out[b]
__global__ __launch_bounds__(192) void k_gru(
    const float* __restrict__ attr_img, const float* __restrict__ attr_user,
    const float* __restrict__ int_img, const float* __restrict__ int_user,
    const float* __restrict__ cs_img, const float* __restrict__ cs_user,
    const float* __restrict__ Wih_i, const float* __restrict__ Whh_i,
    const float* __restrict__ bih_i, const float* __restrict__ bhh_i,
    const float* __restrict__ Wih_u, const float* __restrict__ Whh_u,
    const float* __restrict__ bih_u, const float* __restrict__ bhh_u,
    const float* __restrict__ corr_W, const float* __restrict__ corr_b,
    const float* __restrict__ direct, float* __restrict__ out) {
  int b = blockIdx.x, g = threadIdx.x;  // g in [0,192)
  __shared__ __align__(16) float hbuf[NATTR * DD];
  __shared__ __align__(16) float himg[NATTR * DD];
  __shared__ float gibuf[NATTR * 192];
  __shared__ float ghbuf[NATTR * 192];

  for (int dt = 0; dt < 2; ++dt) {
    const float* e   = (dt ? attr_user : attr_img) + (size_t)b * (NATTR * DD);
    const float* itn = (dt ? int_user : int_img) + (size_t)b * (NATTR * DD);
    const float* cs  = (dt ? cs_img : cs_user) + (size_t)b * DD;  // ext_img uses colsum_user & v.v.
    const float* Wih = dt ? Wih_u : Wih_i;
    const float* Whh = dt ? Whh_u : Whh_i;
    const float* bih = dt ? bih_u : bih_i;
    const float* bhh = dt ? bhh_u : bhh_i;

    float wih_r[DD], whh_r[DD];
#pragma unroll
    for (int d = 0; d < DD; ++d) { wih_r[d] = Wih[d * 192 + g]; whh_r[d] = Whh[d * 192 + g]; }
    float bihg = bih[g], bhhg = bhh[g];

    for (int z = g; z < NATTR * DD; z += 192) hbuf[z] = 0.f;
    __syncthreads();

#pragma unroll
    for (int step = 0; step < 3; ++step) {
      for (int a = 0; a < NATTR; ++a) {
        float gi = bihg, gh = bhhg;
        const float4* e4 = (const float4*)(e + a * DD);
        const float4* it4 = (const float4*)(itn + a * DD);
        const float4* cs4 = (const float4*)cs;
        const float4* h4 = (const float4*)(hbuf + a * DD);
#pragma unroll
        for (int dc = 0; dc < 16; ++dc) {
          float4 xv;
          if (step == 0) xv = e4[dc];
          else if (step == 1) xv = it4[dc];
          else {
            float4 ev = e4[dc]; float4 cv = cs4[dc];
            xv.x = ev.x * cv.x; xv.y = ev.y * cv.y; xv.z = ev.z * cv.z; xv.w = ev.w * cv.w;
          }
          float4 hv = h4[dc];
          gi += xv.x * wih_r[4 * dc + 0] + xv.y * wih_r[4 * dc + 1] +
                xv.z * wih_r[4 * dc + 2] + xv.w * wih_r[4 * dc + 3];
          gh += hv.x * whh_r[4 * dc + 0] + hv.y * whh_r[4 * dc + 1] +
                hv.z * whh_r[4 * dc + 2] + hv.w * whh_r[4 * dc + 3];
        }
        gibuf[a * 192 + g] = gi;
        ghbuf[a * 192 + g] = gh;
      }
      __syncthreads();
#pragma unroll
      for (int q = 0; q < 4; ++q) {
        int eidx = g + q * 192;        // 0..767
        int a = eidx >> 6, d = eidx & 63;
        float ir = gibuf[a * 192 + d], iz = gibuf[a * 192 + 64 + d], in = gibuf[a * 192 + 128 + d];
        float hr = ghbuf[a * 192 + d], hz = ghbuf[a * 192 + 64 + d], hn = ghbuf[a * 192 + 128 + d];
        float hold = hbuf[eidx];
        float rr = 1.f / (1.f + expf(-(ir + hr)));
        float zz = 1.f / (1.f + expf(-(iz + hz)));
        float nn = tanhf(in + rr * hn);
        hbuf[eidx] = (1.f - zz) * nn + zz * hold;
      }
      __syncthreads();
    }
    if (dt == 0) {
      for (int z = g; z < NATTR * DD; z += 192) himg[z] = hbuf[z];
      __syncthreads();
    }
  }
  // epilogue: sum over attrs, dot corr_W, + corr_b + direct
  if (g < 64) {
    float s = 0.f;
#pragma unroll
    for (int a = 0; a < NATTR; ++a) s += himg[a * DD + g] + hbuf[a * DD + g];
    float v = s * corr_W[g];
#pragma unroll
    for (int m = 1; m < 64; m <<= 1) v += __shfl_xor(v, m);
    if (g == 0) out[b] = v + corr_b[0] + direct[b];
  }
}

// ---------------------------------------------------------------- launcher
extern "C" void kernel_launch(void* const* d_in, const int* in_sizes, int n_in,
                              void* d_out, int out_size, void* d_ws, size_t ws_size,
                              hipStream_t stream) {
  const float* images     = (const float*)d_in[0];
  const float* ptraits    = (const float*)d_in[1];
  const float* nima_Wl    = (const float*)d_in[2];
  const float* nima_bl    = (const float*)d_in[3];
  const float* nima_Wa    = (const float*)d_in[4];
  const float* nima_ba    = (const float*)d_in[5];
  const float* imgn_W1    = (const float*)d_in[6];
  const float* imgn_b1    = (const float*)d_in[7];
  const float* imgn_W2    = (const float*)d_in[8];
  const float* imgn_b2    = (const float*)d_in[9];
  const float* usrn_W1    = (const float*)d_in[10];
  const float* usrn_b1    = (const float*)d_in[11];
  const float* usrn_W2    = (const float*)d_in[12];
  const float* usrn_b2    = (const float*)d_in[13];
  const float* iiW1i      = (const float*)d_in[14];
  const float* iib1i      = (const float*)d_in[15];
  const float* iiW2i      = (const float*)d_in[16];
  const float* iib2i      = (const float*)d_in[17];
  const float* iiW1u      = (const float*)d_in[18];
  const float* iib1u      = (const float*)d_in[19];
  const float* iiW2u      = (const float*)d_in[20];
  const float* iib2u      = (const float*)d_in[21];
  const float* gWih_i     = (const float*)d_in[22];
  const float* gWhh_i     = (const float*)d_in[23];
  const float* gbih_i     = (const float*)d_in[24];
  const float* gbhh_i     = (const float*)d_in[25];
  const float* gWih_u     = (const float*)d_in[26];
  const float* gWhh_u     = (const float*)d_in[27];
  const float* gbih_u     = (const float*)d_in[28];
  const float* gbhh_u     = (const float*)d_in[29];
  const float* corr_W     = (const float*)d_in[30];
  const float* corr_b     = (const float*)d_in[31];
  const float* dist_W1    = (const float*)d_in[32];
  const float* dist_b1    = (const float*)d_in[33];
  const float* dist_W2    = (const float*)d_in[34];
  const float* dist_b2    = (const float*)d_in[35];

  float* ws = (float*)d_ws;
  float* WT        = ws;                       // 21*2048      = 43008
  float* logit     = WT + 21 * FEAT;           // B*9          = 18432
  float* attr_raw  = logit + NB * NBINS;       // B*12         = 24576
  float* attr_img  = attr_raw + NB * NATTR;    // B*768
  float* attr_user = attr_img + NB * 768;      // B*768
  float* int_img   = attr_user + NB * 768;     // B*768
  float* int_user  = int_img + NB * 768;       // B*768
  float* cs_img    = int_user + NB * 768;      // B*64
  float* cs_user   = cs_img + NB * DD;         // B*64
  float* direct    = cs_user + NB * DD;        // B

  float* out = (float*)d_out;

  hipLaunchKernelGGL(k_prep_wt, dim3(168), dim3(256), 0, stream, nima_Wl, nima_Wa, WT);
  hipLaunchKernelGGL(k_nima, dim3(NB / 4), dim3(256), 0, stream,
                     images, WT, nima_bl, nima_ba, logit, attr_raw);
  hipLaunchKernelGGL(k_direct, dim3(NB / 4), dim3(256), 0, stream,
                     logit, dist_W1, dist_b1, dist_W2, dist_b2, direct);
  hipLaunchKernelGGL((k_node_mlp<NATTR>), dim3(NB / 8), dim3(256), 0, stream,
                     attr_raw, imgn_W1, imgn_b1, imgn_W2, imgn_b2, attr_img);
  hipLaunchKernelGGL((k_node_mlp<NPT>), dim3(NB / 8), dim3(256), 0, stream,
                     ptraits, usrn_W1, usrn_b1, usrn_W2, usrn_b2, attr_user);
  hipLaunchKernelGGL(k_colsum, dim3(NB), dim3(64), 0, stream,
                     attr_img, attr_user, cs_img, cs_user);
  hipLaunchKernelGGL(k_internal, dim3(NB, 2), dim3(256), 0, stream,
                     attr_img, attr_user,
                     iiW1i, iib1i, iiW2i, iib2i,
                     iiW1u, iib1u, iiW2u, iib2u,
                     int_img, int_user);
  hipLaunchKernelGGL(k_gru, dim3(NB), dim3(192), 0, stream,
                     attr_img, attr_user, int_img, int_user, cs_img, cs_user,
                     gWih_i, gWhh_i, gbih_i, gbhh_i,
                     gWih_u, gWhh_u, gbih_u, gbhh_u,
                     corr_W, corr_b, direct, out);
}

// Round 2
// 418.852 us; speedup vs baseline: 2.6242x; 2.6242x over previous
//
#include <hip/hip_runtime.h>

#define NB 2048      // batch
#define FEAT 2048
#define NBINS 9
#define NATTR 12
#define NPT 20
#define DD 64
#define HH 256

typedef __attribute__((ext_vector_type(8))) short bf8v;   // 8 bf16 (4 VGPRs) MFMA A/B frag
typedef __attribute__((ext_vector_type(4))) float f4v;    // MFMA C/D frag

__device__ __forceinline__ unsigned short f2bf(float f) {
  unsigned int u = __float_as_uint(f);
  u += 0x7FFFu + ((u >> 16) & 1u);   // round-to-nearest-even
  return (unsigned short)(u >> 16);
}

// ---------------------------------------------------------------- K0: weight prep
// WT[c][k], c in [0,21): c<9 -> nima_Wl col c, else nima_Wa col c-9
__global__ void k_prep_wt(const float* __restrict__ Wl, const float* __restrict__ Wa,
                          float* __restrict__ WT) {
  int idx = blockIdx.x * 256 + threadIdx.x;
  if (idx >= 21 * FEAT) return;
  int c = idx / FEAT, k = idx - c * FEAT;
  WT[idx] = (c < NBINS) ? Wl[k * NBINS + c] : Wa[k * NATTR + (c - NBINS)];
}

// ---------------------------------------------------------------- K0b: GRU weight prep
// WTg[idx=dt*2+m][g][72pad] bf16, transposed: WTg[.][g][k] = W[k][g]
__global__ void k_prep_gruw(const float* __restrict__ Wih_i, const float* __restrict__ Whh_i,
                            const float* __restrict__ Wih_u, const float* __restrict__ Whh_u,
                            unsigned short* __restrict__ WTg) {
  int idx = blockIdx.x;  // 0..3
  const float* W = idx == 0 ? Wih_i : idx == 1 ? Whh_i : idx == 2 ? Wih_u : Whh_u;
  int g = threadIdx.x;   // 0..191
  unsigned short* dst = WTg + (size_t)idx * 192 * 72 + (size_t)g * 72;
  for (int k = 0; k < DD; ++k) dst[k] = f2bf(W[k * 192 + g]);
}

// ---------------------------------------------------------------- K1: NIMA heads
__global__ __launch_bounds__(256) void k_nima(
    const float* __restrict__ A, const float* __restrict__ WT,
    const float* __restrict__ bl, const float* __restrict__ ba,
    float* __restrict__ logit, float* __restrict__ attr_raw) {
  int wave = threadIdx.x >> 6, lane = threadIdx.x & 63;
  int row = blockIdx.x * 4 + wave;
  const float4* A4 = (const float4*)(A + (size_t)row * FEAT);
  float acc[21];
#pragma unroll
  for (int c = 0; c < 21; ++c) acc[c] = 0.f;
#pragma unroll
  for (int it = 0; it < 8; ++it) {
    int kk = it * 64 + lane;
    float4 a = A4[kk];
#pragma unroll
    for (int c = 0; c < 21; ++c) {
      float4 w = ((const float4*)(WT + c * FEAT))[kk];
      acc[c] += a.x * w.x + a.y * w.y + a.z * w.z + a.w * w.w;
    }
  }
#pragma unroll
  for (int c = 0; c < 21; ++c) {
#pragma unroll
    for (int m = 1; m < 64; m <<= 1) acc[c] += __shfl_xor(acc[c], m);
  }
  if (lane == 0) {
#pragma unroll
    for (int c = 0; c < NBINS; ++c) logit[row * NBINS + c] = acc[c] + bl[c];
#pragma unroll
    for (int c = 0; c < NATTR; ++c) attr_raw[row * NATTR + c] = acc[NBINS + c] + ba[c];
  }
}

// ---------------------------------------------------------------- K2: direct path
__global__ __launch_bounds__(256) void k_direct(
    const float* __restrict__ logit, const float* __restrict__ W1,
    const float* __restrict__ b1, const float* __restrict__ W2,
    const float* __restrict__ b2, float* __restrict__ direct) {
  int wave = threadIdx.x >> 6, lane = threadIdx.x & 63;
  int b = blockIdx.x * 4 + wave;
  const float* lg = logit + b * NBINS;
  float l[NBINS];
  float m = -1e30f;
#pragma unroll
  for (int i = 0; i < NBINS; ++i) { l[i] = lg[i]; m = fmaxf(m, l[i]); }
  float s = 0.f;
#pragma unroll
  for (int i = 0; i < NBINS; ++i) { l[i] = __expf(l[i] - m); s += l[i]; }
  float inv = 1.f / s;
#pragma unroll
  for (int i = 0; i < NBINS; ++i) l[i] *= inv * (1.f + 0.5f * (float)i);
  float partial = 0.f;
#pragma unroll
  for (int hh = 0; hh < 4; ++hh) {
    int h = lane + hh * 64;
    float v = b1[h];
#pragma unroll
    for (int i = 0; i < NBINS; ++i) v += l[i] * W1[i * HH + h];
    v = fmaxf(v, 0.f);
    partial += v * W2[h];
  }
#pragma unroll
  for (int m2 = 1; m2 < 64; m2 <<= 1) partial += __shfl_xor(partial, m2);
  if (lane == 0) direct[b] = partial + b2[0];
}

// ---------------------------------------------------------------- K3: node MLPs
template <int DIN>
__global__ __launch_bounds__(256) void k_node_mlp(
    const float* __restrict__ X, const float* __restrict__ W1,
    const float* __restrict__ b1, const float* __restrict__ W2,
    const float* __restrict__ b2, float* __restrict__ out) {
  __shared__ __align__(16) float hlds[HH * 8];
  int h = threadIdx.x;
  int r0 = blockIdx.x * 8;
  float w1r[DIN];
#pragma unroll
  for (int d = 0; d < DIN; ++d) w1r[d] = W1[d * HH + h];
  float b1h = b1[h];
#pragma unroll
  for (int r = 0; r < 8; ++r) {
    const float* x = X + (size_t)(r0 + r) * DIN;
    float s = b1h;
#pragma unroll
    for (int d = 0; d < DIN; ++d) s += x[d] * w1r[d];
    hlds[h * 8 + r] = fmaxf(s, 0.f);
  }
  __syncthreads();
  float acc[3][8];
#pragma unroll
  for (int oi = 0; oi < 3; ++oi)
#pragma unroll
    for (int r = 0; r < 8; ++r) acc[oi][r] = 0.f;
  for (int hh = 0; hh < HH; ++hh) {
    float4 a = ((const float4*)(hlds + hh * 8))[0];
    float4 bv = ((const float4*)(hlds + hh * 8))[1];
    float hv[8] = {a.x, a.y, a.z, a.w, bv.x, bv.y, bv.z, bv.w};
#pragma unroll
    for (int oi = 0; oi < 3; ++oi) {
      float w = W2[hh * 768 + threadIdx.x + oi * 256];
#pragma unroll
      for (int r = 0; r < 8; ++r) acc[oi][r] += hv[r] * w;
    }
  }
#pragma unroll
  for (int oi = 0; oi < 3; ++oi) {
    int o = threadIdx.x + oi * 256;
    float bb = b2[o];
#pragma unroll
    for (int r = 0; r < 8; ++r) out[(size_t)(r0 + r) * 768 + o] = acc[oi][r] + bb;
  }
}

// ---------------------------------------------------------------- K4: internal interaction
__global__ __launch_bounds__(256) void k_internal(
    const float* __restrict__ attr_img, const float* __restrict__ attr_user,
    const float* __restrict__ W1i, const float* __restrict__ b1i,
    const float* __restrict__ W2i, const float* __restrict__ b2i,
    const float* __restrict__ W1u, const float* __restrict__ b1u,
    const float* __restrict__ W2u, const float* __restrict__ b2u,
    float* __restrict__ out_img, float* __restrict__ out_user) {
  int b = blockIdx.x, dt = blockIdx.y;
  const float* e = (dt == 0 ? attr_img : attr_user) + (size_t)b * (NATTR * DD);
  const float* W1 = dt == 0 ? W1i : W1u;
  const float* b1 = dt == 0 ? b1i : b1u;
  const float* W2 = dt == 0 ? W2i : W2u;
  const float* b2 = dt == 0 ? b2i : b2u;
  float* outp = (dt == 0 ? out_img : out_user) + (size_t)b * (NATTR * DD);

  __shared__ __align__(16) float qlds[NATTR * HH];
  int h = threadIdx.x;
  float w1c[DD];
#pragma unroll
  for (int d = 0; d < DD; ++d) w1c[d] = W1[d * HH + h];
  float b1h = b1[h];
#pragma unroll
  for (int jj = 0; jj < NATTR; ++jj) qlds[jj * HH + h] = 0.f;

  for (int j = 0; j < NATTR; ++j) {
    float u[DD];
    const float4* ej4 = (const float4*)(e + j * DD);
#pragma unroll
    for (int dc = 0; dc < 16; ++dc) {
      float4 v = ej4[dc];
      u[4 * dc + 0] = v.x * w1c[4 * dc + 0];
      u[4 * dc + 1] = v.y * w1c[4 * dc + 1];
      u[4 * dc + 2] = v.z * w1c[4 * dc + 2];
      u[4 * dc + 3] = v.w * w1c[4 * dc + 3];
    }
    float qj = 0.f;
    for (int i = 0; i <= j; ++i) {
      const float4* ei4 = (const float4*)(e + i * DD);
      float s = b1h;
#pragma unroll
      for (int dc = 0; dc < 16; ++dc) {
        float4 v = ei4[dc];
        s += v.x * u[4 * dc + 0] + v.y * u[4 * dc + 1] +
             v.z * u[4 * dc + 2] + v.w * u[4 * dc + 3];
      }
      float r = fmaxf(s, 0.f);
      qj += r;
      if (i < j) qlds[i * HH + h] += r;
    }
    qlds[j * HH + h] += qj;
  }
  __syncthreads();

#pragma unroll
  for (int oi = 0; oi < 3; ++oi) {
    int o = threadIdx.x + oi * 256;
    int jr = o >> 6, dp = o & 63;
    float acc = 0.f;
    const float4* q4 = (const float4*)(qlds + jr * HH);
    for (int hc = 0; hc < 64; ++hc) {
      float4 qv = q4[hc];
      acc += qv.x * W2[(hc * 4 + 0) * DD + dp];
      acc += qv.y * W2[(hc * 4 + 1) * DD + dp];
      acc += qv.z * W2[(hc * 4 + 2) * DD + dp];
      acc += qv.w * W2[(hc * 4 + 3) * DD + dp];
    }
    outp[o] = acc + 12.f * b2[dp];
  }
}

// ---------------------------------------------------------------- Kext: attr column sums
__global__ __launch_bounds__(64) void k_colsum(
    const float* __restrict__ attr_img, const float* __restrict__ attr_user,
    float* __restrict__ cs_img, float* __restrict__ cs_user) {
  int b = blockIdx.x, d = threadIdx.x;
  const float* ei = attr_img + (size_t)b * (NATTR * DD);
  const float* eu = attr_user + (size_t)b * (NATTR * DD);
  float si = 0.f, su = 0.f;
#pragma unroll
  for (int a = 0; a < NATTR; ++a) { si += ei[a * DD + d]; su += eu[a * DD + d]; }
  cs_img[b * DD + d] = si;
  cs_user[b * DD + d] = su;
}

// ---------------------------------------------------------------- K5: GRU via MFMA
// grid (384, 2): 64 chains/block (chain = b*12+a), dt = img/user.
// 4 waves x 16 chains. Weights bf16-transposed in LDS [g][72pad]; x/h bf16 tiles.
// Per step: gi = x@Wih, gh = h@Whh via mfma 16x16x32; gate triples (r,z,n) land at
// identical C-frag positions -> register-only gate math; h_old kept f32 in regs.
// Epilogue: corr_W dot + 16-lane butterfly + atomicAdd into outacc[b].
__global__ __launch_bounds__(256, 2) void k_gru_mfma(
    const float* __restrict__ attr_img, const float* __restrict__ attr_user,
    const float* __restrict__ int_img, const float* __restrict__ int_user,
    const float* __restrict__ cs_img, const float* __restrict__ cs_user,
    const unsigned short* __restrict__ WTg,
    const float* __restrict__ bih_i, const float* __restrict__ bhh_i,
    const float* __restrict__ bih_u, const float* __restrict__ bhh_u,
    const float* __restrict__ corr_W, float* __restrict__ outacc) {
  int blk = blockIdx.x, dt = blockIdx.y;
  int c0 = blk * 64;
  int tid = threadIdx.x, w = tid >> 6, l = tid & 63;
  int l15 = l & 15, l4 = l >> 4;

  const float* e   = (dt ? attr_user : attr_img);
  const float* itn = (dt ? int_user : int_img);
  const float* cs  = (dt ? cs_img : cs_user);   // cross: ext_img uses user colsum & v.v.
  const float* bih = (dt ? bih_u : bih_i);
  const float* bhh = (dt ? bhh_u : bhh_i);

  __shared__ __align__(16) unsigned short Wlds[2 * 192 * 72];  // [m][g][72] 55296 B
  __shared__ __align__(16) unsigned short Xb[64 * 72];         // 9216 B
  __shared__ __align__(16) unsigned short Hb[64 * 72];         // 9216 B

  // stage weights (one-time per block)
  {
    const unsigned short* src = WTg + (size_t)dt * (2 * 192 * 72);
    for (int v = tid; v < 3456; v += 256)
      *(bf8v*)&Wlds[v * 8] = *(const bf8v*)&src[v * 8];
  }
  // per-lane biases & corr weights
  float bihv[3][4], bhhv[3][4], cw[4];
#pragma unroll
  for (int t = 0; t < 3; ++t)
#pragma unroll
    for (int db = 0; db < 4; ++db) {
      bihv[t][db] = bih[t * 64 + db * 16 + l15];
      bhhv[t][db] = bhh[t * 64 + db * 16 + l15];
    }
#pragma unroll
  for (int db = 0; db < 4; ++db) cw[db] = corr_W[db * 16 + l15];

  float h_old[4][4];
#pragma unroll
  for (int db = 0; db < 4; ++db)
#pragma unroll
    for (int r = 0; r < 4; ++r) h_old[db][r] = 0.f;

  int row = tid >> 2;                    // staging row 0..63 (wave w stages rows 16w..16w+15)
  int chunk = tid & 3;                   // 16-float chunk
  size_t srcoff = (size_t)(c0 + row) * DD + chunk * 16;
  int bb_row = (c0 + row) / NATTR;

  __syncthreads();  // Wlds ready

#pragma unroll
  for (int step = 0; step < 3; ++step) {
    // ---- stage Xb: x = e / internal / e*cs, f32 -> bf16
    {
      const float* src = (step == 1 ? itn : e) + srcoff;
      float4 v0 = ((const float4*)src)[0];
      float4 v1 = ((const float4*)src)[1];
      float4 v2 = ((const float4*)src)[2];
      float4 v3 = ((const float4*)src)[3];
      if (step == 2) {
        const float4* c4 = (const float4*)(cs + (size_t)bb_row * DD + chunk * 16);
        float4 q0 = c4[0], q1 = c4[1], q2 = c4[2], q3 = c4[3];
        v0.x *= q0.x; v0.y *= q0.y; v0.z *= q0.z; v0.w *= q0.w;
        v1.x *= q1.x; v1.y *= q1.y; v1.z *= q1.z; v1.w *= q1.w;
        v2.x *= q2.x; v2.y *= q2.y; v2.z *= q2.z; v2.w *= q2.w;
        v3.x *= q3.x; v3.y *= q3.y; v3.z *= q3.z; v3.w *= q3.w;
      }
      bf8v p0, p1;
      p0[0] = (short)f2bf(v0.x); p0[1] = (short)f2bf(v0.y);
      p0[2] = (short)f2bf(v0.z); p0[3] = (short)f2bf(v0.w);
      p0[4] = (short)f2bf(v1.x); p0[5] = (short)f2bf(v1.y);
      p0[6] = (short)f2bf(v1.z); p0[7] = (short)f2bf(v1.w);
      p1[0] = (short)f2bf(v2.x); p1[1] = (short)f2bf(v2.y);
      p1[2] = (short)f2bf(v2.z); p1[3] = (short)f2bf(v2.w);
      p1[4] = (short)f2bf(v3.x); p1[5] = (short)f2bf(v3.y);
      p1[6] = (short)f2bf(v3.z); p1[7] = (short)f2bf(v3.w);
      *(bf8v*)&Xb[row * 72 + chunk * 16] = p0;
      *(bf8v*)&Xb[row * 72 + chunk * 16 + 8] = p1;
    }
    __syncthreads();  // Xb (and prev-step Hb) visible

    // ---- MFMA: gi (and gh for step>0)
    f4v gi[3][4], gh[3][4];
#pragma unroll
    for (int t = 0; t < 3; ++t)
#pragma unroll
      for (int db = 0; db < 4; ++db) {
        gi[t][db] = (f4v){0.f, 0.f, 0.f, 0.f};
        gh[t][db] = (f4v){0.f, 0.f, 0.f, 0.f};
      }
#pragma unroll
    for (int ks = 0; ks < 2; ++ks) {
      bf8v ax = *(const bf8v*)&Xb[(w * 16 + l15) * 72 + ks * 32 + l4 * 8];
#pragma unroll
      for (int t = 0; t < 3; ++t)
#pragma unroll
        for (int db = 0; db < 4; ++db) {
          bf8v bw = *(const bf8v*)&Wlds[(t * 64 + db * 16 + l15) * 72 + ks * 32 + l4 * 8];
          gi[t][db] = __builtin_amdgcn_mfma_f32_16x16x32_bf16(ax, bw, gi[t][db], 0, 0, 0);
        }
      if (step > 0) {
        bf8v ah = *(const bf8v*)&Hb[(w * 16 + l15) * 72 + ks * 32 + l4 * 8];
#pragma unroll
        for (int t = 0; t < 3; ++t)
#pragma unroll
          for (int db = 0; db < 4; ++db) {
            bf8v bw = *(const bf8v*)&Wlds[(192 + t * 64 + db * 16 + l15) * 72 + ks * 32 + l4 * 8];
            gh[t][db] = __builtin_amdgcn_mfma_f32_16x16x32_bf16(ah, bw, gh[t][db], 0, 0, 0);
          }
      }
    }

    // ---- gates (register-only; step0: gh=0 so bhh bias = reference h0=0 math)
#pragma unroll
    for (int db = 0; db < 4; ++db) {
#pragma unroll
      for (int r = 0; r < 4; ++r) {
        float ir = gi[0][db][r] + bihv[0][db];
        float hr = gh[0][db][r] + bhhv[0][db];
        float iz = gi[1][db][r] + bihv[1][db];
        float hz = gh[1][db][r] + bhhv[1][db];
        float in_ = gi[2][db][r] + bihv[2][db];
        float hn = gh[2][db][r] + bhhv[2][db];
        float rr = 1.f / (1.f + __expf(-(ir + hr)));
        float zz = 1.f / (1.f + __expf(-(iz + hz)));
        float ax_ = in_ + rr * hn;
        ax_ = fminf(fmaxf(ax_, -15.f), 15.f);
        float e2 = __expf(-2.f * ax_);
        float nn = (1.f - e2) / (1.f + e2);
        float h = (1.f - zz) * nn + zz * h_old[db][r];
        h_old[db][r] = h;
        if (step < 2)
          Hb[(w * 16 + l4 * 4 + r) * 72 + db * 16 + l15] = f2bf(h);
      }
    }
    __syncthreads();  // protect Xb/Hb before next step's staging overwrite
  }

  // ---- fused head: out_partial[b] += sum_d corr_W[d]*h[chain][d]
#pragma unroll
  for (int r = 0; r < 4; ++r) {
    float s = 0.f;
#pragma unroll
    for (int db = 0; db < 4; ++db) s += cw[db] * h_old[db][r];
#pragma unroll
    for (int m = 1; m < 16; m <<= 1) s += __shfl_xor(s, m);
    if (l15 == 0) {
      int chain = c0 + w * 16 + l4 * 4 + r;
      atomicAdd(&outacc[chain / NATTR], s);
    }
  }
}

// ---------------------------------------------------------------- K6: finalize
__global__ void k_finalize(const float* __restrict__ outacc, const float* __restrict__ direct,
                           const float* __restrict__ corr_b, float* __restrict__ out) {
  int b = blockIdx.x * 256 + threadIdx.x;
  if (b < NB) out[b] = outacc[b] + direct[b] + corr_b[0];
}

// ---------------------------------------------------------------- launcher
extern "C" void kernel_launch(void* const* d_in, const int* in_sizes, int n_in,
                              void* d_out, int out_size, void* d_ws, size_t ws_size,
                              hipStream_t stream) {
  const float* images     = (const float*)d_in[0];
  const float* ptraits    = (const float*)d_in[1];
  const float* nima_Wl    = (const float*)d_in[2];
  const float* nima_bl    = (const float*)d_in[3];
  const float* nima_Wa    = (const float*)d_in[4];
  const float* nima_ba    = (const float*)d_in[5];
  const float* imgn_W1    = (const float*)d_in[6];
  const float* imgn_b1    = (const float*)d_in[7];
  const float* imgn_W2    = (const float*)d_in[8];
  const float* imgn_b2    = (const float*)d_in[9];
  const float* usrn_W1    = (const float*)d_in[10];
  const float* usrn_b1    = (const float*)d_in[11];
  const float* usrn_W2    = (const float*)d_in[12];
  const float* usrn_b2    = (const float*)d_in[13];
  const float* iiW1i      = (const float*)d_in[14];
  const float* iib1i      = (const float*)d_in[15];
  const float* iiW2i      = (const float*)d_in[16];
  const float* iib2i      = (const float*)d_in[17];
  const float* iiW1u      = (const float*)d_in[18];
  const float* iib1u      = (const float*)d_in[19];
  const float* iiW2u      = (const float*)d_in[20];
  const float* iib2u      = (const float*)d_in[21];
  const float* gWih_i     = (const float*)d_in[22];
  const float* gWhh_i     = (const float*)d_in[23];
  const float* gbih_i     = (const float*)d_in[24];
  const float* gbhh_i     = (const float*)d_in[25];
  const float* gWih_u     = (const float*)d_in[26];
  const float* gWhh_u     = (const float*)d_in[27];
  const float* gbih_u     = (const float*)d_in[28];
  const float* gbhh_u     = (const float*)d_in[29];
  const float* corr_W     = (const float*)d_in[30];
  const float* corr_b     = (const float*)d_in[31];
  const float* dist_W1    = (const float*)d_in[32];
  const float* dist_b1    = (const float*)d_in[33];
  const float* dist_W2    = (const float*)d_in[34];
  const float* dist_b2    = (const float*)d_in[35];

  float* ws = (float*)d_ws;
  float* WT        = ws;                       // 21*2048
  float* logit     = WT + 21 * FEAT;           // B*9
  float* attr_raw  = logit + NB * NBINS;       // B*12
  float* attr_img  = attr_raw + NB * NATTR;    // B*768
  float* attr_user = attr_img + NB * 768;      // B*768
  float* int_img   = attr_user + NB * 768;     // B*768
  float* int_user  = int_img + NB * 768;       // B*768
  float* cs_img    = int_user + NB * 768;      // B*64
  float* cs_user   = cs_img + NB * DD;         // B*64
  float* direct    = cs_user + NB * DD;        // B
  float* outacc    = direct + NB;              // B
  unsigned short* WTg = (unsigned short*)(outacc + NB);  // 4*192*72 bf16

  float* out = (float*)d_out;

  hipLaunchKernelGGL(k_prep_wt, dim3(168), dim3(256), 0, stream, nima_Wl, nima_Wa, WT);
  hipLaunchKernelGGL(k_prep_gruw, dim3(4), dim3(192), 0, stream,
                     gWih_i, gWhh_i, gWih_u, gWhh_u, WTg);
  hipMemsetAsync(outacc, 0, NB * sizeof(float), stream);
  hipLaunchKernelGGL(k_nima, dim3(NB / 4), dim3(256), 0, stream,
                     images, WT, nima_bl, nima_ba, logit, attr_raw);
  hipLaunchKernelGGL(k_direct, dim3(NB / 4), dim3(256), 0, stream,
                     logit, dist_W1, dist_b1, dist_W2, dist_b2, direct);
  hipLaunchKernelGGL((k_node_mlp<NATTR>), dim3(NB / 8), dim3(256), 0, stream,
                     attr_raw, imgn_W1, imgn_b1, imgn_W2, imgn_b2, attr_img);
  hipLaunchKernelGGL((k_node_mlp<NPT>), dim3(NB / 8), dim3(256), 0, stream,
                     ptraits, usrn_W1, usrn_b1, usrn_W2, usrn_b2, attr_user);
  hipLaunchKernelGGL(k_colsum, dim3(NB), dim3(64), 0, stream,
                     attr_img, attr_user, cs_img, cs_user);
  hipLaunchKernelGGL(k_internal, dim3(NB, 2), dim3(256), 0, stream,
                     attr_img, attr_user,
                     iiW1i, iib1i, iiW2i, iib2i,
                     iiW1u, iib1u, iiW2u, iib2u,
                     int_img, int_user);
  hipLaunchKernelGGL(k_gru_mfma, dim3(NB * NATTR / 64, 2), dim3(256), 0, stream,
                     attr_img, attr_user, int_img, int_user, cs_img, cs_user,
                     WTg, gbih_i, gbhh_i, gbih_u, gbhh_u, corr_W, outacc);
  hipLaunchKernelGGL(k_finalize, dim3(NB / 256), dim3(256), 0, stream,
                     outacc, direct, corr_b, out);
}